// Round 7
// baseline (187.852 us; speedup 1.0000x reference)
//
#include <hip/hip_runtime.h>
#include <hip/hip_bf16.h>

// FC_KANLayer: B=6, T=1024, D_IN=256, D_OUT=512, NUM_GRIDS=8
// FUNC_LIST = [rbf, bs, dog, base, rbf, bs]
// f32 in/out; GEMMs via bf16 MFMA.
// R7: many small blocks per kernel (kill 3-shift makespan), separate launches
// for rocprof attribution, LDS-tiled param transpose (kill scattered stores).

typedef short short8 __attribute__((ext_vector_type(8)));
typedef float floatx4 __attribute__((ext_vector_type(4)));

using bf16 = __hip_bfloat16;

#define LOG2E 1.44269504088896340736f

constexpr int Tn   = 1024;
constexpr int DIN  = 256;
constexpr int DOUT = 512;
constexpr int NG   = 8;
constexpr int KSP  = DIN * NG;            // 2048
constexpr float INV_DENOM = 7.0f / 3.0f;  // 1/DENOM, DENOM = 3/7

// ================= LN + basis/silu (1536 blocks, wave-per-row) ===============
__global__ __launch_bounds__(256) void k_ln(
        const float* __restrict__ X,
        const float* __restrict__ w,
        const float* __restrict__ b,
        const float* __restrict__ grid_rbf,
        const float* __restrict__ grid_bs,
        bf16* __restrict__ Amat,   // [4096][2048]
        bf16* __restrict__ Sm,     // [1024][256]
        float* __restrict__ Xn2) { // [1024][256]
    int tid = threadIdx.x;
    int wv = tid >> 6, lane = tid & 63;
    int row = blockIdx.x * 4 + wv;       // b*1024 + t
    int batch = row >> 10, t = row & 1023;

    float x[4];
    #pragma unroll
    for (int j = 0; j < 4; j++) x[j] = X[(size_t)row * DIN + j * 64 + lane];
    float s = x[0] + x[1] + x[2] + x[3];
    float ss = x[0] * x[0] + x[1] * x[1] + x[2] * x[2] + x[3] * x[3];
    #pragma unroll
    for (int o = 1; o < 64; o <<= 1) {
        s  += __shfl_xor(s, o);
        ss += __shfl_xor(ss, o);
    }
    float mu = s * (1.0f / DIN);
    float rstd = rsqrtf(ss * (1.0f / DIN) - mu * mu + 1e-5f);

    float xn[4];
    #pragma unroll
    for (int j = 0; j < 4; j++) {
        int din = j * 64 + lane;
        xn[j] = (x[j] - mu) * rstd * w[din] + b[din];
    }

    if (batch == 2) {
        #pragma unroll
        for (int j = 0; j < 4; j++)
            Xn2[(size_t)t * DIN + j * 64 + lane] = xn[j];
    } else if (batch == 3) {
        #pragma unroll
        for (int j = 0; j < 4; j++) {
            float e = __builtin_amdgcn_exp2f(-xn[j] * LOG2E);
            float si = xn[j] * __builtin_amdgcn_rcpf(1.0f + e);
            Sm[(size_t)t * DIN + j * 64 + lane] = __float2bfloat16(si);
        }
    } else {
        int which = (batch == 0) ? 0 : (batch == 1) ? 1 : (batch == 4) ? 2 : 3;
        bool is_rbf = (batch == 0) || (batch == 4);
        #pragma unroll
        for (int j = 0; j < 4; j++) {
            float v = xn[j];
            float outv[NG];
            if (is_rbf) {
                #pragma unroll
                for (int g = 0; g < NG; g++) {
                    float d = (v - grid_rbf[g]) * INV_DENOM;
                    outv[g] = __builtin_amdgcn_exp2f(-d * d * LOG2E);
                }
            } else {
                float g[12];
                #pragma unroll
                for (int i = 0; i < 12; i++) g[i] = grid_bs[i];
                float ih = 1.0f / (g[1] - g[0]);           // uniform spacing
                float ihk[3] = {ih, ih * 0.5f, ih * (1.0f / 3.0f)};
                float bs_[11];
                #pragma unroll
                for (int i = 0; i < 11; i++)
                    bs_[i] = (v >= g[i] && v < g[i + 1]) ? 1.0f : 0.0f;
                #pragma unroll
                for (int k = 1; k <= 3; k++) {
                    float rk = ihk[k - 1];
                    #pragma unroll
                    for (int i = 0; i < 10; i++) {
                        if (i <= 10 - k) {
                            bs_[i] = (v - g[i]) * rk * bs_[i]
                                   + (g[i + k + 1] - v) * rk * bs_[i + 1];
                        }
                    }
                }
                #pragma unroll
                for (int gg = 0; gg < NG; gg++) outv[gg] = bs_[gg];
            }
            short8 pv;
            #pragma unroll
            for (int gg = 0; gg < NG; gg++) {
                bf16 h = __float2bfloat16(outv[gg]);
                pv[gg] = __builtin_bit_cast(short, h);
            }
            *(short8*)((short*)Amat + (size_t)(which * Tn + t) * KSP
                       + (size_t)(j * 64 + lane) * NG) = pv;
        }
    }
}

// ============ prep: bf16 convert (blocks 0..4607) + LDS transpose (4608..4639)
__global__ __launch_bounds__(256) void k_prep(
        const float* __restrict__ sw,
        const float* __restrict__ bw,
        const float* __restrict__ sc,
        const float* __restrict__ tr,
        bf16* __restrict__ swb,    // [512][2048]
        bf16* __restrict__ bwb,    // [512][256]
        float* __restrict__ rsT,   // [256][512]
        float* __restrict__ ttT,
        float* __restrict__ nbwT) {
    __shared__ float t1[64][65], t2[64][65];
    int bid = blockIdx.x, tid = threadIdx.x;
    if (bid < 4608) {
        int i = bid * 256 + tid;          // 0 .. 1179647
        if (i < 1048576) swb[i] = __float2bfloat16(sw[i]);
        else             bwb[i - 1048576] = __float2bfloat16(bw[i - 1048576]);
        return;
    }
    // transpose role: tile (rt,ct): dout0 = rt*64, din0 = ct*64
    int tb = bid - 4608;                  // 0..31
    int dout0 = (tb >> 2) * 64, din0 = (tb & 3) * 64;
    #pragma unroll
    for (int j = 0; j < 16; j++) {
        int idx = j * 256 + tid;
        int r = idx >> 6, c = idx & 63;   // consecutive tid -> consecutive c
        float vs = sc[(dout0 + r) * DIN + din0 + c];
        float vt = tr[(dout0 + r) * DIN + din0 + c];
        float inv = 1.0f / vs;
        t1[r][c] = inv;
        t2[r][c] = -vt * inv;
    }
    __syncthreads();
    #pragma unroll
    for (int j = 0; j < 16; j++) {
        int idx = j * 256 + tid;
        int c = idx >> 6, r = idx & 63;   // consecutive tid -> consecutive r
        rsT[(din0 + c) * DOUT + dout0 + r] = t1[r][c];
        ttT[(din0 + c) * DOUT + dout0 + r] = t2[r][c];
    }
    __syncthreads();
    #pragma unroll
    for (int j = 0; j < 16; j++) {
        int idx = j * 256 + tid;
        int r = idx >> 6, c = idx & 63;
        t1[r][c] = -bw[(dout0 + r) * DIN + din0 + c];
    }
    __syncthreads();
    #pragma unroll
    for (int j = 0; j < 16; j++) {
        int idx = j * 256 + tid;
        int c = idx >> 6, r = idx & 63;
        nbwT[(din0 + c) * DOUT + dout0 + r] = t1[r][c];
    }
}

// ====== GEMM: C[M,512] = A[M,K] * W[512,K]^T, 64x64 tiles, direct loads ======
// grid(M/64, 8); bid%8 = mt%8 -> XCD holds its A-slice (2 MiB) + B (2 MiB) in L2.
// wave tile 32x32 (2x2 frags); register ping-pong prefetch distance 1.
template <int K, int MODE>
__global__ __launch_bounds__(256) void k_gemm(const short* __restrict__ A,
                                              const short* __restrict__ Bw,
                                              float* __restrict__ out) {
    int row0 = blockIdx.x * 64, col0 = blockIdx.y * 64;
    int tid = threadIdx.x;
    int wv = tid >> 6, lane = tid & 63;
    int m = lane & 15, q = lane >> 4;
    int wr = wv >> 1, wc = wv & 1;

    const short8* ap[2];
    const short8* bp[2];
    #pragma unroll
    for (int r = 0; r < 2; r++)
        ap[r] = (const short8*)(A + (size_t)(row0 + wr * 32 + r * 16 + m) * K);
    #pragma unroll
    for (int c = 0; c < 2; c++)
        bp[c] = (const short8*)(Bw + (size_t)(col0 + wc * 32 + c * 16 + m) * K);

    floatx4 acc[2][2];
    #pragma unroll
    for (int r = 0; r < 2; r++)
        #pragma unroll
        for (int c = 0; c < 2; c++) acc[r][c] = (floatx4)(0.0f);

    constexpr int STEPS = K / 32;         // short8 idx of step s = s*4 + q
    short8 a0[2], b0[2], a1[2], b1[2];
    #pragma unroll
    for (int r = 0; r < 2; r++) a0[r] = ap[r][q];
    #pragma unroll
    for (int c = 0; c < 2; c++) b0[c] = bp[c][q];

    for (int s = 0; s < STEPS; s += 2) {
        int i1 = (s + 1) * 4 + q;
        #pragma unroll
        for (int r = 0; r < 2; r++) a1[r] = ap[r][i1];
        #pragma unroll
        for (int c = 0; c < 2; c++) b1[c] = bp[c][i1];
        #pragma unroll
        for (int r = 0; r < 2; r++) {
            acc[r][0] = __builtin_amdgcn_mfma_f32_16x16x32_bf16(a0[r], b0[0], acc[r][0], 0, 0, 0);
            acc[r][1] = __builtin_amdgcn_mfma_f32_16x16x32_bf16(a0[r], b0[1], acc[r][1], 0, 0, 0);
        }
        if (s + 2 < STEPS) {
            int i2 = (s + 2) * 4 + q;
            #pragma unroll
            for (int r = 0; r < 2; r++) a0[r] = ap[r][i2];
            #pragma unroll
            for (int c = 0; c < 2; c++) b0[c] = bp[c][i2];
        }
        #pragma unroll
        for (int r = 0; r < 2; r++) {
            acc[r][0] = __builtin_amdgcn_mfma_f32_16x16x32_bf16(a1[r], b1[0], acc[r][0], 0, 0, 0);
            acc[r][1] = __builtin_amdgcn_mfma_f32_16x16x32_bf16(a1[r], b1[1], acc[r][1], 0, 0, 0);
        }
    }

    #pragma unroll
    for (int r = 0; r < 2; r++) {
        #pragma unroll
        for (int c = 0; c < 2; c++) {
            #pragma unroll
            for (int rr = 0; rr < 4; rr++) {
                int row = row0 + wr * 32 + r * 16 + q * 4 + rr;
                int col = col0 + wc * 32 + c * 16 + m;
                size_t off;
                if (MODE == 0) {
                    int which = row >> 10, t = row & 1023;
                    int batch = (which == 0) ? 0 : (which == 1) ? 1 : (which == 2) ? 4 : 5;
                    off = ((size_t)batch * Tn + t) * DOUT + col;
                } else {
                    off = ((size_t)3 * Tn + row) * DOUT + col;
                }
                out[off] = acc[r][c][rr];
            }
        }
    }
}

// ================= DoG (batch 2): 1024 blocks, 64 dout x 8 t =================
// bid%8 = dout-tile -> per-XCD param-column locality; x-tile 8x256 in LDS.
__global__ __launch_bounds__(256) void k_dog(const float* __restrict__ Xn2,
                                             const float* __restrict__ rsT,
                                             const float* __restrict__ ttT,
                                             const float* __restrict__ nbwT,
                                             float* __restrict__ out) {
    __shared__ float xs_[8 * 256];
    int bid = blockIdx.x, tid = threadIdx.x;
    int dt = bid & 7, t0 = (bid >> 3) * 8;
    {
        int row = tid >> 5, c8 = (tid & 31) * 8;
        *(float4*)&xs_[row * 256 + c8] =
            *(const float4*)&Xn2[(size_t)(t0 + row) * 256 + c8];
        *(float4*)&xs_[row * 256 + c8 + 4] =
            *(const float4*)&Xn2[(size_t)(t0 + row) * 256 + c8 + 4];
    }
    __syncthreads();

    int dl = tid & 63, tg = tid >> 6;
    int dout = dt * 64 + dl;
    const float kC = -0.5f * LOG2E;
    float acc0 = 0.f, acc1 = 0.f;
    const float* x0 = xs_ + (tg * 2) * 256;
    const float* x1 = x0 + 256;
    #pragma unroll 4
    for (int d = 0; d < DIN; d++) {
        float r = rsT[d * DOUT + dout];
        float o = ttT[d * DOUT + dout];
        float w = nbwT[d * DOUT + dout];
        float xa = fmaf(x0[d], r, o);
        float ea = __builtin_amdgcn_exp2f(xa * xa * kC);
        acc0 = fmaf(xa * ea, w, acc0);
        float xb = fmaf(x1[d], r, o);
        float eb = __builtin_amdgcn_exp2f(xb * xb * kC);
        acc1 = fmaf(xb * eb, w, acc1);
    }
    size_t base = (size_t)2 * Tn * DOUT + (size_t)(t0 + tg * 2) * DOUT + dout;
    out[base] = acc0;
    out[base + DOUT] = acc1;
}

extern "C" void kernel_launch(void* const* d_in, const int* in_sizes, int n_in,
                              void* d_out, int out_size, void* d_ws, size_t ws_size,
                              hipStream_t stream) {
    const float* X        = (const float*)d_in[0];
    const float* ln_w     = (const float*)d_in[1];
    const float* ln_b     = (const float*)d_in[2];
    const float* base_w   = (const float*)d_in[3];
    const float* spline_w = (const float*)d_in[4];
    const float* scale    = (const float*)d_in[5];
    const float* transl   = (const float*)d_in[6];
    const float* grid_rbf = (const float*)d_in[7];
    const float* grid_bs  = (const float*)d_in[8];
    float* out = (float*)d_out;

    char* ws = (char*)d_ws;
    bf16*  Amat = (bf16*)ws;                                   // 16 MiB   [4096][2048]
    bf16*  SWb  = (bf16*)(ws + 16777216);                      // 2 MiB    [512][2048]
    bf16*  BWb  = (bf16*)(ws + 16777216 + 2097152);            // 0.25 MiB [512][256]
    bf16*  Sm   = (bf16*)(ws + 19136512);                      // 0.5 MiB  [1024][256]
    float* Xn2  = (float*)(ws + 19660800);                     // 1 MiB    [1024][256]
    float* rsT  = (float*)(ws + 20709376);                     // 0.5 MiB  [256][512]
    float* ttT  = (float*)(ws + 21233664);                     // 0.5 MiB
    float* nbwT = (float*)(ws + 21757952);                     // 0.5 MiB

    k_ln<<<1536, 256, 0, stream>>>(X, ln_w, ln_b, grid_rbf, grid_bs, Amat, Sm, Xn2);
    k_prep<<<4640, 256, 0, stream>>>(spline_w, base_w, scale, transl,
                                     SWb, BWb, rsT, ttT, nbwT);
    k_gemm<KSP, 0><<<dim3(64, 8), 256, 0, stream>>>((const short*)Amat,
                                                    (const short*)SWb, out);
    k_gemm<DIN, 1><<<dim3(16, 8), 256, 0, stream>>>((const short*)Sm,
                                                    (const short*)BWb, out);
    k_dog<<<1024, 256, 0, stream>>>(Xn2, rsT, ttT, nbwT, out);
}

// Round 8
// 143.743 us; speedup vs baseline: 1.3069x; 1.3069x over previous
//
#include <hip/hip_runtime.h>
#include <hip/hip_bf16.h>

// FC_KANLayer: B=6, T=1024, D_IN=256, D_OUT=512, NUM_GRIDS=8
// FUNC_LIST = [rbf, bs, dog, base, rbf, bs]
// f32 in/out; GEMMs via bf16 MFMA.
// R8: K1 = LN+basis+prep; K2 = heterogeneous mega-kernel (split-K spline GEMM
// with swizzled LDS dbuf + base GEMM + dog, ~2176 blocks for concurrency);
// K3 = split-K reduce.

typedef short short8 __attribute__((ext_vector_type(8)));
typedef float floatx4 __attribute__((ext_vector_type(4)));

using bf16 = __hip_bfloat16;

#define LOG2E 1.44269504088896340736f

constexpr int Tn   = 1024;
constexpr int DIN  = 256;
constexpr int DOUT = 512;
constexpr int NG   = 8;
constexpr int KSP  = DIN * NG;            // 2048
constexpr float INV_DENOM = 7.0f / 3.0f;  // 1/DENOM, DENOM = 3/7

// ================= K1 ========================================================
// [0,1536): LN+basis wave-per-row | [1536,2112): f32->bf16 convert (x8 vec)
// [2112,2144): dog-param LDS transpose
__global__ __launch_bounds__(256) void k1_kernel(
        const float* __restrict__ X,
        const float* __restrict__ w,
        const float* __restrict__ b,
        const float* __restrict__ grid_rbf,
        const float* __restrict__ grid_bs,
        const float* __restrict__ sw,
        const float* __restrict__ bw,
        const float* __restrict__ sc,
        const float* __restrict__ tr,
        bf16* __restrict__ Amat,   // [4096][2048]
        bf16* __restrict__ Sm,     // [1024][256]
        float* __restrict__ Xn2,   // [1024][256]
        bf16* __restrict__ swb,    // [512][2048]
        bf16* __restrict__ bwb,    // [512][256]
        float* __restrict__ rsT,   // [256][512]
        float* __restrict__ ttT,
        float* __restrict__ nbwT) {
    __shared__ float t1[64][65], t2[64][65];
    int tid = threadIdx.x, bid = blockIdx.x;

    if (bid >= 2112) {
        // ---- transpose role: tile dout0 x din0 ------------------------------
        int tb = bid - 2112;                  // 0..31
        int dout0 = (tb >> 2) * 64, din0 = (tb & 3) * 64;
        #pragma unroll
        for (int j = 0; j < 16; j++) {
            int idx = j * 256 + tid;
            int r = idx >> 6, c = idx & 63;
            float vs = sc[(dout0 + r) * DIN + din0 + c];
            float vt = tr[(dout0 + r) * DIN + din0 + c];
            float inv = 1.0f / vs;
            t1[r][c] = inv;
            t2[r][c] = -vt * inv;
        }
        __syncthreads();
        #pragma unroll
        for (int j = 0; j < 16; j++) {
            int idx = j * 256 + tid;
            int c = idx >> 6, r = idx & 63;
            rsT[(din0 + c) * DOUT + dout0 + r] = t1[r][c];
            ttT[(din0 + c) * DOUT + dout0 + r] = t2[r][c];
        }
        __syncthreads();
        #pragma unroll
        for (int j = 0; j < 16; j++) {
            int idx = j * 256 + tid;
            int r = idx >> 6, c = idx & 63;
            t1[r][c] = -bw[(dout0 + r) * DIN + din0 + c];
        }
        __syncthreads();
        #pragma unroll
        for (int j = 0; j < 16; j++) {
            int idx = j * 256 + tid;
            int c = idx >> 6, r = idx & 63;
            nbwT[(din0 + c) * DOUT + dout0 + r] = t1[r][c];
        }
        return;
    }
    if (bid >= 1536) {
        // ---- convert role: 8 f32 -> 8 bf16 per thread -----------------------
        int e = ((bid - 1536) * 256 + tid) * 8;    // [0, 1179648)
        const float* src = (e < 1048576) ? (sw + e) : (bw + (e - 1048576));
        bf16* dst = (e < 1048576) ? (swb + e) : (bwb + (e - 1048576));
        float4 v0 = *(const float4*)src;
        float4 v1 = *(const float4*)(src + 4);
        short8 p;
        p[0] = __builtin_bit_cast(short, __float2bfloat16(v0.x));
        p[1] = __builtin_bit_cast(short, __float2bfloat16(v0.y));
        p[2] = __builtin_bit_cast(short, __float2bfloat16(v0.z));
        p[3] = __builtin_bit_cast(short, __float2bfloat16(v0.w));
        p[4] = __builtin_bit_cast(short, __float2bfloat16(v1.x));
        p[5] = __builtin_bit_cast(short, __float2bfloat16(v1.y));
        p[6] = __builtin_bit_cast(short, __float2bfloat16(v1.z));
        p[7] = __builtin_bit_cast(short, __float2bfloat16(v1.w));
        *(short8*)dst = p;
        return;
    }

    // ---- LN + basis role ----------------------------------------------------
    int wv = tid >> 6, lane = tid & 63;
    int row = bid * 4 + wv;              // b*1024 + t
    int batch = row >> 10, t = row & 1023;

    float x[4];
    #pragma unroll
    for (int j = 0; j < 4; j++) x[j] = X[(size_t)row * DIN + j * 64 + lane];
    float s = x[0] + x[1] + x[2] + x[3];
    float ss = x[0] * x[0] + x[1] * x[1] + x[2] * x[2] + x[3] * x[3];
    #pragma unroll
    for (int o = 1; o < 64; o <<= 1) {
        s  += __shfl_xor(s, o);
        ss += __shfl_xor(ss, o);
    }
    float mu = s * (1.0f / DIN);
    float rstd = rsqrtf(ss * (1.0f / DIN) - mu * mu + 1e-5f);

    float xn[4];
    #pragma unroll
    for (int j = 0; j < 4; j++) {
        int din = j * 64 + lane;
        xn[j] = (x[j] - mu) * rstd * w[din] + b[din];
    }

    if (batch == 2) {
        #pragma unroll
        for (int j = 0; j < 4; j++)
            Xn2[(size_t)t * DIN + j * 64 + lane] = xn[j];
    } else if (batch == 3) {
        #pragma unroll
        for (int j = 0; j < 4; j++) {
            float e = __builtin_amdgcn_exp2f(-xn[j] * LOG2E);
            float si = xn[j] * __builtin_amdgcn_rcpf(1.0f + e);
            Sm[(size_t)t * DIN + j * 64 + lane] = __float2bfloat16(si);
        }
    } else {
        int which = (batch == 0) ? 0 : (batch == 1) ? 1 : (batch == 4) ? 2 : 3;
        bool is_rbf = (batch == 0) || (batch == 4);
        #pragma unroll
        for (int j = 0; j < 4; j++) {
            float v = xn[j];
            float outv[NG];
            if (is_rbf) {
                #pragma unroll
                for (int g = 0; g < NG; g++) {
                    float d = (v - grid_rbf[g]) * INV_DENOM;
                    outv[g] = __builtin_amdgcn_exp2f(-d * d * LOG2E);
                }
            } else {
                float g[12];
                #pragma unroll
                for (int i = 0; i < 12; i++) g[i] = grid_bs[i];
                float ih = 1.0f / (g[1] - g[0]);
                float ihk[3] = {ih, ih * 0.5f, ih * (1.0f / 3.0f)};
                float bs_[11];
                #pragma unroll
                for (int i = 0; i < 11; i++)
                    bs_[i] = (v >= g[i] && v < g[i + 1]) ? 1.0f : 0.0f;
                #pragma unroll
                for (int k = 1; k <= 3; k++) {
                    float rk = ihk[k - 1];
                    #pragma unroll
                    for (int i = 0; i < 10; i++) {
                        if (i <= 10 - k) {
                            bs_[i] = (v - g[i]) * rk * bs_[i]
                                   + (g[i + k + 1] - v) * rk * bs_[i + 1];
                        }
                    }
                }
                #pragma unroll
                for (int gg = 0; gg < NG; gg++) outv[gg] = bs_[gg];
            }
            short8 pv;
            #pragma unroll
            for (int gg = 0; gg < NG; gg++) {
                bf16 h = __float2bfloat16(outv[gg]);
                pv[gg] = __builtin_bit_cast(short, h);
            }
            *(short8*)((short*)Amat + (size_t)(which * Tn + t) * KSP
                       + (size_t)(j * 64 + lane) * NG) = pv;
        }
    }
}

// ---------------- GEMM core: 64x64 tile, BK=32, dbuf LDS, XOR-swizzled -------
// acc layout: wave (wr,wc) owns 32x32; frags acc[r][c] (r:M, c:N).
// LDS slot (row ri, chunk cs) holds global k-chunk cs ^ ((ri>>1)&3)  -> 2-way max.
template <int KS>
__device__ __forceinline__ void gemm_core(const short* __restrict__ A,
                                          const short* __restrict__ Bw,
                                          int row0, int col0, int kbase, int iters,
                                          int tid, char* smem, floatx4 acc[2][2]) {
    short* ldsA = (short*)smem;            // [2][64][32]
    short* ldsB = (short*)(smem + 8192);   // [2][64][32]
    int wv = tid >> 6, lane = tid & 63;
    int r16 = lane >> 2, cs = lane & 3;
    int cg = cs ^ ((r16 >> 1) & 3);
    const short* gA = A  + (size_t)(row0 + wv * 16 + r16) * KS + kbase + cg * 8;
    const short* gB = Bw + (size_t)(col0 + wv * 16 + r16) * KS + kbase + cg * 8;

    int m = lane & 15, q = lane >> 4;
    int wr = wv >> 1, wc = wv & 1;
    int ra0 = wr * 32 + m, ra1 = ra0 + 16;
    int rb0 = wc * 32 + m, rb1 = rb0 + 16;
    int oA0 = ra0 * 32 + (q ^ ((ra0 >> 1) & 3)) * 8;   // shorts
    int oA1 = ra1 * 32 + (q ^ ((ra1 >> 1) & 3)) * 8;
    int oB0 = rb0 * 32 + (q ^ ((rb0 >> 1) & 3)) * 8;
    int oB1 = rb1 * 32 + (q ^ ((rb1 >> 1) & 3)) * 8;

    // prologue: stage tile 0 into buf 0
    __builtin_amdgcn_global_load_lds(
        (const __attribute__((address_space(1))) void*)gA,
        (__attribute__((address_space(3))) void*)(ldsA + wv * 512), 16, 0, 0);
    __builtin_amdgcn_global_load_lds(
        (const __attribute__((address_space(1))) void*)gB,
        (__attribute__((address_space(3))) void*)(ldsB + wv * 512), 16, 0, 0);

    for (int i = 0; i < iters; i++) {
        int cur = i & 1;
        __syncthreads();
        if (i + 1 < iters) {
            int nxt = cur ^ 1, kof = (i + 1) * 32;
            __builtin_amdgcn_global_load_lds(
                (const __attribute__((address_space(1))) void*)(gA + kof),
                (__attribute__((address_space(3))) void*)(ldsA + nxt * 2048 + wv * 512),
                16, 0, 0);
            __builtin_amdgcn_global_load_lds(
                (const __attribute__((address_space(1))) void*)(gB + kof),
                (__attribute__((address_space(3))) void*)(ldsB + nxt * 2048 + wv * 512),
                16, 0, 0);
        }
        const short* bA = ldsA + cur * 2048;
        const short* bB = ldsB + cur * 2048;
        short8 a0 = *(const short8*)(bA + oA0);
        short8 a1 = *(const short8*)(bA + oA1);
        short8 b0 = *(const short8*)(bB + oB0);
        short8 b1 = *(const short8*)(bB + oB1);
        acc[0][0] = __builtin_amdgcn_mfma_f32_16x16x32_bf16(a0, b0, acc[0][0], 0, 0, 0);
        acc[0][1] = __builtin_amdgcn_mfma_f32_16x16x32_bf16(a0, b1, acc[0][1], 0, 0, 0);
        acc[1][0] = __builtin_amdgcn_mfma_f32_16x16x32_bf16(a1, b0, acc[1][0], 0, 0, 0);
        acc[1][1] = __builtin_amdgcn_mfma_f32_16x16x32_bf16(a1, b1, acc[1][1], 0, 0, 0);
    }
}

// ================= K2: heterogeneous mega-kernel =============================
// [0,1024):    spline GEMM 64x64, split-K=2 -> partials P0/P1
// [1024,1152): base GEMM 64x64, K=256 -> out batch 3
// [1152,2176): DoG, 64 dout x 8 t -> out batch 2
__global__ __launch_bounds__(256) void k2_kernel(const bf16* __restrict__ Amat,
                                                 const bf16* __restrict__ SWb,
                                                 const bf16* __restrict__ Sm,
                                                 const bf16* __restrict__ BWb,
                                                 const float* __restrict__ Xn2,
                                                 const float* __restrict__ rsT,
                                                 const float* __restrict__ ttT,
                                                 const float* __restrict__ nbwT,
                                                 float* __restrict__ P0,
                                                 float* __restrict__ P1,
                                                 float* __restrict__ out) {
    __shared__ alignas(16) char smem[16384];
    int bid = blockIdx.x, tid = threadIdx.x;

    if (bid < 1024) {
        // ---- spline GEMM role ----------------------------------------------
        int nt = bid >> 7, i7 = bid & 127;
        int mt = i7 >> 1, kc = bid & 1;
        int row0 = mt * 64, col0 = nt * 64;
        floatx4 acc[2][2];
        #pragma unroll
        for (int r = 0; r < 2; r++)
            #pragma unroll
            for (int c = 0; c < 2; c++) acc[r][c] = (floatx4)(0.0f);
        gemm_core<KSP>((const short*)Amat, (const short*)SWb,
                       row0, col0, kc * 1024, 32, tid, smem, acc);
        float* P = kc ? P1 : P0;
        int wv = tid >> 6, lane = tid & 63;
        int m = lane & 15, q = lane >> 4;
        int wr = wv >> 1, wc = wv & 1;
        #pragma unroll
        for (int r = 0; r < 2; r++)
            #pragma unroll
            for (int c = 0; c < 2; c++)
                #pragma unroll
                for (int rr = 0; rr < 4; rr++) {
                    int row = row0 + wr * 32 + r * 16 + q * 4 + rr;
                    int col = col0 + wc * 32 + c * 16 + m;
                    P[(size_t)row * DOUT + col] = acc[r][c][rr];
                }
    } else if (bid < 1152) {
        // ---- base GEMM role ------------------------------------------------
        int idx = bid - 1024;
        int mt = idx >> 3, nt = idx & 7;
        int row0 = mt * 64, col0 = nt * 64;
        floatx4 acc[2][2];
        #pragma unroll
        for (int r = 0; r < 2; r++)
            #pragma unroll
            for (int c = 0; c < 2; c++) acc[r][c] = (floatx4)(0.0f);
        gemm_core<DIN>((const short*)Sm, (const short*)BWb,
                       row0, col0, 0, 8, tid, smem, acc);
        int wv = tid >> 6, lane = tid & 63;
        int m = lane & 15, q = lane >> 4;
        int wr = wv >> 1, wc = wv & 1;
        #pragma unroll
        for (int r = 0; r < 2; r++)
            #pragma unroll
            for (int c = 0; c < 2; c++)
                #pragma unroll
                for (int rr = 0; rr < 4; rr++) {
                    int row = row0 + wr * 32 + r * 16 + q * 4 + rr;
                    int col = col0 + wc * 32 + c * 16 + m;
                    out[((size_t)3 * Tn + row) * DOUT + col] = acc[r][c][rr];
                }
    } else {
        // ---- DoG role ------------------------------------------------------
        int j = bid - 1152;                 // 0..1023
        int dt = j & 7, t0 = (j >> 3) * 8;
        float* xs_ = (float*)smem;          // [8][256] = 8 KiB
        {
            int row = tid >> 5, c8 = (tid & 31) * 8;
            *(float4*)&xs_[row * 256 + c8] =
                *(const float4*)&Xn2[(size_t)(t0 + row) * 256 + c8];
            *(float4*)&xs_[row * 256 + c8 + 4] =
                *(const float4*)&Xn2[(size_t)(t0 + row) * 256 + c8 + 4];
        }
        __syncthreads();

        int dl = tid & 63, tg = tid >> 6;
        int dout = dt * 64 + dl;
        const float kC = -0.5f * LOG2E;
        float acc0 = 0.f, acc1 = 0.f;
        const float* x0 = xs_ + (tg * 2) * 256;
        const float* x1 = x0 + 256;
        #pragma unroll 4
        for (int d = 0; d < DIN; d++) {
            float r = rsT[d * DOUT + dout];
            float o = ttT[d * DOUT + dout];
            float w = nbwT[d * DOUT + dout];
            float xa = fmaf(x0[d], r, o);
            float ea = __builtin_amdgcn_exp2f(xa * xa * kC);
            acc0 = fmaf(xa * ea, w, acc0);
            float xb = fmaf(x1[d], r, o);
            float eb = __builtin_amdgcn_exp2f(xb * xb * kC);
            acc1 = fmaf(xb * eb, w, acc1);
        }
        size_t base = (size_t)2 * Tn * DOUT + (size_t)(t0 + tg * 2) * DOUT + dout;
        out[base] = acc0;
        out[base + DOUT] = acc1;
    }
}

// ================= K3: split-K reduce (P0+P1 -> out, spline batches) =========
__global__ __launch_bounds__(256) void k3_kernel(const float* __restrict__ P0,
                                                 const float* __restrict__ P1,
                                                 float* __restrict__ out) {
    int t4 = blockIdx.x * 256 + threadIdx.x;    // [0, 131072)
    #pragma unroll
    for (int k = 0; k < 4; k++) {
        int i4 = t4 + k * 131072;               // float4 index, [0, 524288)
        int row = i4 >> 7, c4 = i4 & 127;
        int which = row >> 10, t = row & 1023;
        int batch = (which == 0) ? 0 : (which == 1) ? 1 : (which == 2) ? 4 : 5;
        float4 a = *(const float4*)(P0 + (size_t)i4 * 4);
        float4 b = *(const float4*)(P1 + (size_t)i4 * 4);
        float4 s = make_float4(a.x + b.x, a.y + b.y, a.z + b.z, a.w + b.w);
        *(float4*)&out[((size_t)batch * Tn + t) * DOUT + c4 * 4] = s;
    }
}

extern "C" void kernel_launch(void* const* d_in, const int* in_sizes, int n_in,
                              void* d_out, int out_size, void* d_ws, size_t ws_size,
                              hipStream_t stream) {
    const float* X        = (const float*)d_in[0];
    const float* ln_w     = (const float*)d_in[1];
    const float* ln_b     = (const float*)d_in[2];
    const float* base_w   = (const float*)d_in[3];
    const float* spline_w = (const float*)d_in[4];
    const float* scale    = (const float*)d_in[5];
    const float* transl   = (const float*)d_in[6];
    const float* grid_rbf = (const float*)d_in[7];
    const float* grid_bs  = (const float*)d_in[8];
    float* out = (float*)d_out;

    char* ws = (char*)d_ws;
    bf16*  Amat = (bf16*)ws;                                   // 16 MiB   [4096][2048]
    bf16*  SWb  = (bf16*)(ws + 16777216);                      // 2 MiB    [512][2048]
    bf16*  BWb  = (bf16*)(ws + 18874368);                      // 0.25 MiB [512][256]
    bf16*  Sm   = (bf16*)(ws + 19136512);                      // 0.5 MiB  [1024][256]
    float* Xn2  = (float*)(ws + 19660800);                     // 1 MiB    [1024][256]
    float* rsT  = (float*)(ws + 20709376);                     // 0.5 MiB  [256][512]
    float* ttT  = (float*)(ws + 21233664);                     // 0.5 MiB
    float* nbwT = (float*)(ws + 21757952);                     // 0.5 MiB
    float* P0   = (float*)(ws + 22282240);                     // 8 MiB    [4096][512]
    float* P1   = (float*)(ws + 30670848);                     // 8 MiB

    k1_kernel<<<2144, 256, 0, stream>>>(X, ln_w, ln_b, grid_rbf, grid_bs,
                                        spline_w, base_w, scale, transl,
                                        Amat, Sm, Xn2, SWb, BWb, rsT, ttT, nbwT);
    k2_kernel<<<2176, 256, 0, stream>>>(Amat, SWb, Sm, BWb, Xn2,
                                        rsT, ttT, nbwT, P0, P1, out);
    k3_kernel<<<512, 256, 0, stream>>>(P0, P1, out);
}